// Round 2
// baseline (827.531 us; speedup 1.0000x reference)
//
#include <hip/hip_runtime.h>

// DeepSeek-V2 expert MLP, fp8-block-dequant weights.
// Harness dtypes: ALL inputs f32, output f32 (per reference). Internally we
// cast to bf16 and use v_mfma_f32_16x16x32_bf16 (f32 accumulate).
// T=8192 tokens, H=5120 hidden, F=1536 intermediate.
// Pipeline:
//   1) xcast:    x f32 -> bf16 in ws
//   2) dequant8 x3: w[f,h]*s[f/128,h/128] f32 -> bf16 in ws
//   3) gateup_gemm: h = silu(x@wg^T) * (x@wu^T)   [8192,1536] bf16 in ws
//   4) down_gemm:   out = h @ wd^T                [8192,5120] f32 to d_out
// GEMM structure = m97 ladder step 3: 128x128 C-tile / 256 threads (4 waves,
// each 64x64 = 4x4 MFMA tiles), BK=32, global_load_lds width=16 staging.

typedef __bf16 bf16x8 __attribute__((ext_vector_type(8)));
typedef float  f32x4  __attribute__((ext_vector_type(4)));

#define BK 32

// Stage a 128x32 bf16 tile (contiguous [128][32] in LDS) from global
// (leading dim ldk) via direct-to-LDS 16B loads. 512 chunks of 16B; thread t
// handles chunks t and t+256 (LDS dest contiguous in lane order: required by
// global_load_lds wave-uniform-base + lane*16 semantics).
__device__ __forceinline__ void stage128x32(const __bf16* __restrict__ gbase,
                                            __bf16* lds, int ldk, int tid) {
#pragma unroll
  for (int i = 0; i < 2; ++i) {
    int c = tid + i * 256;
    int row = c >> 2;
    int q = c & 3;
    const __bf16* g = gbase + (size_t)row * ldk + q * 8;
    __builtin_amdgcn_global_load_lds(
        (const __attribute__((address_space(1))) void*)g,
        (__attribute__((address_space(3))) void*)(lds + c * 8),
        16, 0, 0);
  }
}

// f32 -> bf16 cast, 8 elems/thread.
__global__ void xcast(const float* __restrict__ in, __bf16* __restrict__ out,
                      size_t n) {
  size_t idx = ((size_t)blockIdx.x * blockDim.x + threadIdx.x) * 8;
  if (idx >= n) return;
  f32x4 a = *(const f32x4*)(in + idx);
  f32x4 b = *(const f32x4*)(in + idx + 4);
  bf16x8 o;
#pragma unroll
  for (int i = 0; i < 4; ++i) { o[i] = (__bf16)a[i]; o[i + 4] = (__bf16)b[i]; }
  *(bf16x8*)(out + idx) = o;
}

// Per-(128,128)-block dequant: o[r,c] = (bf16)(w[r,c] * s[r/128, c/128]).
// w, s are f32; o is bf16.
__global__ void dequant8(const float* __restrict__ w,
                         const float* __restrict__ s,
                         __bf16* __restrict__ o, int rows, int cols) {
  size_t idx = ((size_t)blockIdx.x * blockDim.x + threadIdx.x) * 8;
  if (idx >= (size_t)rows * (size_t)cols) return;
  int r = (int)(idx / cols);
  int c = (int)(idx % cols);
  float sc = s[(r >> 7) * (cols >> 7) + (c >> 7)];
  f32x4 a = *(const f32x4*)(w + idx);
  f32x4 b = *(const f32x4*)(w + idx + 4);
  bf16x8 ov;
#pragma unroll
  for (int i = 0; i < 4; ++i) {
    ov[i] = (__bf16)(a[i] * sc);
    ov[i + 4] = (__bf16)(b[i] * sc);
  }
  *(bf16x8*)(o + idx) = ov;
}

// Fused gate+up GEMM + SiLU*mul epilogue.
// X:[M,K] bf16, Wg/Wu:[N,K] bf16 (B^T form), Hout:[M,N] bf16.
__global__ __launch_bounds__(256, 2)
void gateup_gemm(const __bf16* __restrict__ X, const __bf16* __restrict__ Wg,
                 const __bf16* __restrict__ Wu, __bf16* __restrict__ Hout,
                 int M, int N, int K) {
  __shared__ __bf16 sA[128 * BK];
  __shared__ __bf16 sBg[128 * BK];
  __shared__ __bf16 sBu[128 * BK];
  const int tid = threadIdx.x;
  const int lane = tid & 63;
  const int wave = tid >> 6;
  const int wm = (wave >> 1) * 64;
  const int wn = (wave & 1) * 64;
  const int m0 = blockIdx.y * 128;
  const int n0 = blockIdx.x * 128;
  const int lr = lane & 15;
  const int lk = (lane >> 4) * 8;

  f32x4 accg[4][4] = {};
  f32x4 accu[4][4] = {};

  const __bf16* Ab = X + (size_t)m0 * K;
  const __bf16* Gb = Wg + (size_t)n0 * K;
  const __bf16* Ub = Wu + (size_t)n0 * K;

  for (int k0 = 0; k0 < K; k0 += BK) {
    stage128x32(Ab + k0, sA, K, tid);
    stage128x32(Gb + k0, sBg, K, tid);
    stage128x32(Ub + k0, sBu, K, tid);
    __syncthreads();
    bf16x8 af[4];
#pragma unroll
    for (int i = 0; i < 4; ++i)
      af[i] = *(const bf16x8*)(sA + (wm + i * 16 + lr) * BK + lk);
#pragma unroll
    for (int j = 0; j < 4; ++j) {
      bf16x8 bg = *(const bf16x8*)(sBg + (wn + j * 16 + lr) * BK + lk);
      bf16x8 bu = *(const bf16x8*)(sBu + (wn + j * 16 + lr) * BK + lk);
#pragma unroll
      for (int i = 0; i < 4; ++i) {
        accg[i][j] =
            __builtin_amdgcn_mfma_f32_16x16x32_bf16(af[i], bg, accg[i][j], 0, 0, 0);
        accu[i][j] =
            __builtin_amdgcn_mfma_f32_16x16x32_bf16(af[i], bu, accu[i][j], 0, 0, 0);
      }
    }
    __syncthreads();
  }

  // C/D layout (m89-verified): col = lane&15, row = (lane>>4)*4 + reg.
  const int colb = n0 + wn + lr;
  const int rowb = m0 + wm + (lane >> 4) * 4;
#pragma unroll
  for (int i = 0; i < 4; ++i)
#pragma unroll
    for (int j = 0; j < 4; ++j)
#pragma unroll
      for (int r = 0; r < 4; ++r) {
        float g = accg[i][j][r];
        float u = accu[i][j][r];
        float hv = (g / (1.0f + __expf(-g))) * u;
        Hout[(size_t)(rowb + i * 16 + r) * N + (colb + j * 16)] = (__bf16)hv;
      }
}

// m97-style GEMM: C = A @ B^T.  A:[M,K] bf16, B:[N,K] bf16, C:[M,N] f32.
__global__ void down_gemm(const __bf16* __restrict__ A,
                          const __bf16* __restrict__ B,
                          float* __restrict__ C, int M, int N, int K) {
  __shared__ __bf16 sA[128 * BK];
  __shared__ __bf16 sB[128 * BK];
  const int tid = threadIdx.x;
  const int lane = tid & 63;
  const int wave = tid >> 6;
  const int wm = (wave >> 1) * 64;
  const int wn = (wave & 1) * 64;
  const int m0 = blockIdx.y * 128;
  const int n0 = blockIdx.x * 128;
  const int lr = lane & 15;
  const int lk = (lane >> 4) * 8;

  f32x4 acc[4][4] = {};

  const __bf16* Ab = A + (size_t)m0 * K;
  const __bf16* Bb = B + (size_t)n0 * K;

  for (int k0 = 0; k0 < K; k0 += BK) {
    stage128x32(Ab + k0, sA, K, tid);
    stage128x32(Bb + k0, sB, K, tid);
    __syncthreads();
    bf16x8 af[4];
#pragma unroll
    for (int i = 0; i < 4; ++i)
      af[i] = *(const bf16x8*)(sA + (wm + i * 16 + lr) * BK + lk);
#pragma unroll
    for (int j = 0; j < 4; ++j) {
      bf16x8 bf = *(const bf16x8*)(sB + (wn + j * 16 + lr) * BK + lk);
#pragma unroll
      for (int i = 0; i < 4; ++i)
        acc[i][j] =
            __builtin_amdgcn_mfma_f32_16x16x32_bf16(af[i], bf, acc[i][j], 0, 0, 0);
    }
    __syncthreads();
  }

  const int colb = n0 + wn + lr;
  const int rowb = m0 + wm + (lane >> 4) * 4;
#pragma unroll
  for (int i = 0; i < 4; ++i)
#pragma unroll
    for (int j = 0; j < 4; ++j)
#pragma unroll
      for (int r = 0; r < 4; ++r)
        C[(size_t)(rowb + i * 16 + r) * N + (colb + j * 16)] = acc[i][j][r];
}

extern "C" void kernel_launch(void* const* d_in, const int* in_sizes, int n_in,
                              void* d_out, int out_size, void* d_ws,
                              size_t ws_size, hipStream_t stream) {
  const int Hd = 5120, Fd = 1536, Td = 8192;
  const float* x = (const float*)d_in[0];
  const float* wg = (const float*)d_in[1];
  const float* sg = (const float*)d_in[2];
  const float* wu = (const float*)d_in[3];
  const float* su = (const float*)d_in[4];
  const float* wd = (const float*)d_in[5];
  const float* sd = (const float*)d_in[6];
  float* out = (float*)d_out;

  // Workspace layout (bf16 elements):
  //   xb [T*H] | wgq [F*H] | wuq [F*H] | wdq [H*F] | hbuf [T*F]  ~149 MB
  __bf16* ws = (__bf16*)d_ws;
  const size_t xsz = (size_t)Td * (size_t)Hd;
  const size_t wsz = (size_t)Fd * (size_t)Hd;
  __bf16* xb = ws;
  __bf16* wgq = xb + xsz;
  __bf16* wuq = wgq + wsz;
  __bf16* wdq = wuq + wsz;
  __bf16* hbuf = wdq + wsz;

  xcast<<<(int)(xsz / 8 / 256), 256, 0, stream>>>(x, xb, xsz);  // exact

  const int dq_blocks = (int)(wsz / 8 / 256);  // 3840, exact
  dequant8<<<dq_blocks, 256, 0, stream>>>(wg, sg, wgq, Fd, Hd);
  dequant8<<<dq_blocks, 256, 0, stream>>>(wu, su, wuq, Fd, Hd);
  dequant8<<<dq_blocks, 256, 0, stream>>>(wd, sd, wdq, Hd, Fd);

  dim3 g1(Fd / 128, Td / 128);  // 12 x 64
  gateup_gemm<<<g1, 256, 0, stream>>>(xb, wgq, wuq, hbuf, Td, Fd, Hd);

  dim3 g2(Hd / 128, Td / 128);  // 40 x 64
  down_gemm<<<g2, 256, 0, stream>>>(hbuf, wdq, out, Td, Hd, Fd);
}

// Round 3
// 809.954 us; speedup vs baseline: 1.0217x; 1.0217x over previous
//
#include <hip/hip_runtime.h>

// DeepSeek-V2 expert MLP, fp8-block-dequant weights. All inputs f32, out f32.
// T=8192, H=5120, F=1536.
// Pipeline (3 dispatches):
//   1) prep: x f32->bf16; wg,wu dequant->bf16 INTERLEAVED into wq[3072][5120]
//      (row 2f = gate_f, row 2f+1 = up_f); wd dequant->bf16 wdq[5120][1536].
//   2) gemm_bt<FUSE_SILU>: cat = xb @ wq^T, N=3072; epilogue pairs adjacent
//      even/odd columns (gate_f, up_f) via shfl_xor(1) and writes
//      h[8192][1536] = silu(gate)*up as bf16. Grid 24x64=1536 blocks = 3 full
//      residency waves (no tail, unlike round-2's 768-block gateup).
//   3) gemm_bt<plain>: out = h @ wdq^T, f32 to d_out. Grid 40x64=2560.
// GEMM structure = m97: 128x128 C-tile / 256 thr (4 waves, each 64x64 = 4x4
// MFMA tiles), BK=32, global_load_lds width=16, v_mfma_f32_16x16x32_bf16.

typedef __bf16 bf16x8 __attribute__((ext_vector_type(8)));
typedef float  f32x4  __attribute__((ext_vector_type(4)));

#define BK 32

// Stage a 128x32 bf16 tile (contiguous [128][32] in LDS) from global
// (leading dim ldk) via direct-to-LDS 16B loads. 512 chunks; thread t handles
// chunks t and t+256 (LDS dest contiguous in lane order as required by
// global_load_lds wave-uniform-base + lane*16 semantics).
__device__ __forceinline__ void stage128x32(const __bf16* __restrict__ gbase,
                                            __bf16* lds, int ldk, int tid) {
#pragma unroll
  for (int i = 0; i < 2; ++i) {
    int c = tid + i * 256;
    int row = c >> 2;
    int q = c & 3;
    const __bf16* g = gbase + (size_t)row * ldk + q * 8;
    __builtin_amdgcn_global_load_lds(
        (const __attribute__((address_space(1))) void*)g,
        (__attribute__((address_space(3))) void*)(lds + c * 8),
        16, 0, 0);
  }
}

// ---- fused prep: xcast + 3 dequants in one launch -------------------------
// Region block counts: x: 20480, wg: 3840, wu: 3840, wd: 3840  (total 32000).
__device__ __forceinline__ void cast8(const float* __restrict__ in,
                                      __bf16* __restrict__ out, size_t idx) {
  f32x4 a = *(const f32x4*)(in + idx);
  f32x4 b = *(const f32x4*)(in + idx + 4);
  bf16x8 o;
#pragma unroll
  for (int i = 0; i < 4; ++i) { o[i] = (__bf16)a[i]; o[i + 4] = (__bf16)b[i]; }
  *(bf16x8*)(out + idx) = o;
}

// dequant 8 elems of a [F=1536 x H=5120] weight, write interleaved row 2f+which.
__device__ __forceinline__ void dq_ilv(const float* __restrict__ w,
                                       const float* __restrict__ s,
                                       __bf16* __restrict__ wq, int r, int tid,
                                       int which) {
  unsigned idx = ((unsigned)r * 256u + (unsigned)tid) * 8u;  // < 7.9M
  unsigned f = idx / 5120u;          // magic-mul (constant divisor)
  unsigned h = idx - f * 5120u;
  float sc = s[(f >> 7) * 40 + (h >> 7)];
  f32x4 a = *(const f32x4*)(w + idx);
  f32x4 b = *(const f32x4*)(w + idx + 4);
  bf16x8 o;
#pragma unroll
  for (int i = 0; i < 4; ++i) {
    o[i] = (__bf16)(a[i] * sc);
    o[i + 4] = (__bf16)(b[i] * sc);
  }
  *(bf16x8*)(wq + (size_t)(2 * f + which) * 5120 + h) = o;
}

// dequant 8 elems of wd [H=5120 x F=1536], plain layout.
__device__ __forceinline__ void dq_wd(const float* __restrict__ w,
                                      const float* __restrict__ s,
                                      __bf16* __restrict__ o8, int r, int tid) {
  unsigned idx = ((unsigned)r * 256u + (unsigned)tid) * 8u;
  unsigned f = idx / 1536u;
  unsigned h = idx - f * 1536u;
  float sc = s[(f >> 7) * 12 + (h >> 7)];
  f32x4 a = *(const f32x4*)(w + idx);
  f32x4 b = *(const f32x4*)(w + idx + 4);
  bf16x8 o;
#pragma unroll
  for (int i = 0; i < 4; ++i) {
    o[i] = (__bf16)(a[i] * sc);
    o[i + 4] = (__bf16)(b[i] * sc);
  }
  *(bf16x8*)(o8 + idx) = o;
}

__global__ void prep(const float* __restrict__ x, const float* __restrict__ wg,
                     const float* __restrict__ sg, const float* __restrict__ wu,
                     const float* __restrict__ su, const float* __restrict__ wd,
                     const float* __restrict__ sd, __bf16* __restrict__ xb,
                     __bf16* __restrict__ wq, __bf16* __restrict__ wdq) {
  int bid = blockIdx.x;
  int tid = threadIdx.x;
  if (bid < 20480) {
    cast8(x, xb, ((size_t)bid * 256 + tid) * 8);
  } else if (bid < 24320) {
    dq_ilv(wg, sg, wq, bid - 20480, tid, 0);
  } else if (bid < 28160) {
    dq_ilv(wu, su, wq, bid - 24320, tid, 1);
  } else {
    dq_wd(wd, sd, wdq, bid - 28160, tid);
  }
}

// ---- m97-style GEMM: C = A @ B^T ------------------------------------------
// A:[M,K] bf16, B:[N,K] bf16.
// FUSE_SILU=false: C = f32 [M,N].
// FUSE_SILU=true:  treats even/odd column pairs as (gate,up); writes
//                  Hout bf16 [M, N/2] with h = silu(gate)*up.
template <bool FUSE_SILU, typename OutT>
__global__ void gemm_bt(const __bf16* __restrict__ A,
                        const __bf16* __restrict__ B, OutT* __restrict__ C,
                        int M, int N, int K, int ldc) {
  __shared__ __bf16 sA[128 * BK];
  __shared__ __bf16 sB[128 * BK];
  const int tid = threadIdx.x;
  const int lane = tid & 63;
  const int wave = tid >> 6;
  const int wm = (wave >> 1) * 64;
  const int wn = (wave & 1) * 64;
  const int m0 = blockIdx.y * 128;
  const int n0 = blockIdx.x * 128;
  const int lr = lane & 15;
  const int lk = (lane >> 4) * 8;

  f32x4 acc[4][4] = {};

  const __bf16* Ab = A + (size_t)m0 * K;
  const __bf16* Bb = B + (size_t)n0 * K;

  for (int k0 = 0; k0 < K; k0 += BK) {
    stage128x32(Ab + k0, sA, K, tid);
    stage128x32(Bb + k0, sB, K, tid);
    __syncthreads();
    bf16x8 af[4];
#pragma unroll
    for (int i = 0; i < 4; ++i)
      af[i] = *(const bf16x8*)(sA + (wm + i * 16 + lr) * BK + lk);
#pragma unroll
    for (int j = 0; j < 4; ++j) {
      bf16x8 bf = *(const bf16x8*)(sB + (wn + j * 16 + lr) * BK + lk);
#pragma unroll
      for (int i = 0; i < 4; ++i)
        acc[i][j] =
            __builtin_amdgcn_mfma_f32_16x16x32_bf16(af[i], bf, acc[i][j], 0, 0, 0);
    }
    __syncthreads();
  }

  // C/D layout (m89-verified): col = lane&15, row = (lane>>4)*4 + reg.
  const int colb = n0 + wn + lr;
  const int rowb = m0 + wm + (lane >> 4) * 4;
#pragma unroll
  for (int i = 0; i < 4; ++i)
#pragma unroll
    for (int j = 0; j < 4; ++j)
#pragma unroll
      for (int r = 0; r < 4; ++r) {
        if constexpr (FUSE_SILU) {
          // lanes (2k, 2k+1) hold cols (2f, 2f+1) = (gate_f, up_f) of the
          // same output row -> exchange via shfl_xor(1), even lane writes.
          float v = acc[i][j][r];
          float p = __shfl_xor(v, 1, 64);
          float g = (lane & 1) ? p : v;
          float u = (lane & 1) ? v : p;
          float hv = (g / (1.0f + __expf(-g))) * u;
          if ((lane & 1) == 0)
            C[(size_t)(rowb + i * 16 + r) * ldc + ((colb + j * 16) >> 1)] =
                (OutT)hv;
        } else {
          C[(size_t)(rowb + i * 16 + r) * ldc + (colb + j * 16)] =
              (OutT)acc[i][j][r];
        }
      }
}

extern "C" void kernel_launch(void* const* d_in, const int* in_sizes, int n_in,
                              void* d_out, int out_size, void* d_ws,
                              size_t ws_size, hipStream_t stream) {
  const int Hd = 5120, Fd = 1536, Td = 8192;
  const float* x = (const float*)d_in[0];
  const float* wg = (const float*)d_in[1];
  const float* sg = (const float*)d_in[2];
  const float* wu = (const float*)d_in[3];
  const float* su = (const float*)d_in[4];
  const float* wd = (const float*)d_in[5];
  const float* sd = (const float*)d_in[6];
  float* out = (float*)d_out;

  // ws layout (bf16): xb [T*H] | wq [2F*H] | wdq [H*F] | h [T*F]  ~156 MB
  __bf16* ws = (__bf16*)d_ws;
  const size_t xsz = (size_t)Td * Hd;
  __bf16* xb = ws;
  __bf16* wq = xb + xsz;
  __bf16* wdq = wq + (size_t)2 * Fd * Hd;
  __bf16* hbuf = wdq + (size_t)Hd * Fd;

  prep<<<32000, 256, 0, stream>>>(x, wg, sg, wu, su, wd, sd, xb, wq, wdq);

  dim3 g1(2 * Fd / 128, Td / 128);  // 24 x 64 = 1536 blocks
  gemm_bt<true, __bf16><<<g1, 256, 0, stream>>>(xb, wq, hbuf, Td, 2 * Fd, Hd,
                                                Fd);

  dim3 g2(Hd / 128, Td / 128);  // 40 x 64 = 2560 blocks
  gemm_bt<false, float><<<g2, 256, 0, stream>>>(hbuf, wdq, out, Td, Hd, Fd, Hd);
}